// Round 6
// baseline (10999.734 us; speedup 1.0000x reference)
//
#include <hip/hip_runtime.h>

typedef __attribute__((ext_vector_type(4)))  float f32x4;
typedef __attribute__((ext_vector_type(8)))  unsigned short us8;
typedef __attribute__((ext_vector_type(2)))  unsigned short us2;

__device__ __forceinline__ float bf2f(unsigned short u) {
    union { unsigned i; float f; } v; v.i = ((unsigned)u) << 16; return v.f;
}
// flexible scalar load: f32nz ? fp32 : bf16
__device__ __forceinline__ float ldflex(const void* p, int isf32, long i) {
    return isf32 ? ((const float*)p)[i] : bf2f(((const unsigned short*)p)[i]);
}
__device__ __forceinline__ float gelu_exact(float v) {
    return 0.5f * v * (1.0f + erff(v * 0.70710678118654752f));
}

constexpr int LDP = 68;   // LDS row stride (floats)

// ---------------------------------------------------------------------------
// Dtype sniffer. Examines first K pairs (lo,hi) of u16s (safe under both
// interpretations: reads < 2*n_elems bytes). fp32 signature: low half-words
// have uniform exponent fields (insane) OR are ~all zero while highs aren't
// (exact constants like 1.0f). Writes 1=fp32, 0=bf16.
// ---------------------------------------------------------------------------
__global__ __launch_bounds__(64) void sniff_dtype(
    const unsigned short* __restrict__ buf, int n_elems, int* __restrict__ flag)
{
    __shared__ int cnt[3];   // insane_even, nz_even, nz_odd
    if (threadIdx.x < 3) cnt[threadIdx.x] = 0;
    __syncthreads();
    int K = n_elems / 2; if (K > 1024) K = 1024; if (K < 1) K = 1;
    int ins = 0, ne = 0, no = 0;
    for (int i = threadIdx.x; i < K; i += 64) {
        const unsigned lo = buf[2 * i], hi = buf[2 * i + 1];
        const unsigned e = (lo >> 7) & 0xFF;
        ins += (lo != 0 && (e < 90 || e > 160)) ? 1 : 0;
        ne  += (lo != 0);
        no  += (hi != 0);
    }
    atomicAdd(&cnt[0], ins); atomicAdd(&cnt[1], ne); atomicAdd(&cnt[2], no);
    __syncthreads();
    if (threadIdx.x == 0) {
        const int isf32 = (cnt[0] * 10 > K) || (cnt[1] * 10 < K && cnt[2] * 2 > K);
        *flag = isf32;
    }
}

// ---------------------------------------------------------------------------
// VALU fp32 GEMM: C = A[M,K] @ W[Nout,K]^T (+bias)(+gelu)(+resid).
// A, C fp32; W/bias/resid flexible dtype via flags. 256 thr, 64x64 tile,
// KT=32, 4x4/thread. resid indexed with global row0 (dtype-safe offsets).
// C/resid NOT __restrict__ (mlp2 runs in-place C==resid; per-element
// read-before-write within one thread).
// ---------------------------------------------------------------------------
__global__ __launch_bounds__(256) void gemm_bt(
    const float* __restrict__ A, const void* __restrict__ W,
    const int* __restrict__ wflag,
    float* C, int Nout, int K,
    const void* __restrict__ bias, const int* __restrict__ bflag,
    const void* resid, const int* rflag, long resid_row0, int act)
{
    __shared__ float As[32][LDP];   // As[k][m]
    __shared__ float Bs[32][LDP];   // Bs[k][n]
    const int tid = threadIdx.x;
    const int tx = tid & 15, ty = tid >> 4;
    const int bm = blockIdx.y * 64, bn = blockIdx.x * 64;
    const int wf = *wflag;
    const int row = tid >> 2;           // 0..63
    const int kk  = (tid & 3) * 8;      // 0,8,16,24

    float acc[4][4] = {};

    for (int k0 = 0; k0 < K; k0 += 32) {
        float a8[8], b8[8];
        {
            const float* ap = &A[(long)(bm + row) * K + k0 + kk];
            const f32x4 a0 = *(const f32x4*)ap, a1 = *(const f32x4*)(ap + 4);
            a8[0]=a0[0]; a8[1]=a0[1]; a8[2]=a0[2]; a8[3]=a0[3];
            a8[4]=a1[0]; a8[5]=a1[1]; a8[6]=a1[2]; a8[7]=a1[3];
        }
        if (wf) {
            const float* wp = &((const float*)W)[(long)(bn + row) * K + k0 + kk];
            const f32x4 b0 = *(const f32x4*)wp, b1 = *(const f32x4*)(wp + 4);
            b8[0]=b0[0]; b8[1]=b0[1]; b8[2]=b0[2]; b8[3]=b0[3];
            b8[4]=b1[0]; b8[5]=b1[1]; b8[6]=b1[2]; b8[7]=b1[3];
        } else {
            const us8 b = *(const us8*)&((const unsigned short*)W)[(long)(bn + row) * K + k0 + kk];
            #pragma unroll
            for (int t = 0; t < 8; ++t) b8[t] = bf2f(b[t]);
        }
        __syncthreads();   // prior iter's LDS reads done
        #pragma unroll
        for (int t = 0; t < 8; ++t) { As[kk + t][row] = a8[t]; Bs[kk + t][row] = b8[t]; }
        __syncthreads();

        #pragma unroll
        for (int k = 0; k < 32; ++k) {
            const f32x4 av = *(const f32x4*)&As[k][ty << 2];
            const f32x4 bv = *(const f32x4*)&Bs[k][tx << 2];
            #pragma unroll
            for (int i = 0; i < 4; ++i)
                #pragma unroll
                for (int j = 0; j < 4; ++j)
                    acc[i][j] = fmaf(av[i], bv[j], acc[i][j]);
        }
    }

    const int bf = bias  ? *bflag : 1;
    const int rf = resid ? (rflag ? *rflag : 1) : 1;
    #pragma unroll
    for (int i = 0; i < 4; ++i) {
        const int r  = bm + (ty << 2) + i;
        const int c0 = bn + (tx << 2);
        f32x4 outv;
        #pragma unroll
        for (int j = 0; j < 4; ++j) {
            float v = acc[i][j];
            if (bias)  v += ldflex(bias, bf, c0 + j);
            if (act)   v  = gelu_exact(v);
            if (resid) v += ldflex(resid, rf, (resid_row0 + r) * (long)Nout + c0 + j);
            outv[j] = v;
        }
        *(f32x4*)&C[(long)r * Nout + c0] = outv;
    }
}

// ---------------------------------------------------------------------------
// LayerNorm over rows of 512. x/g/b flexible dtype; output fp32.
// One block (256 thr) per row; 2 elements/thread. row0 = global row offset.
// ---------------------------------------------------------------------------
__global__ __launch_bounds__(256) void layernorm_512(
    const void* __restrict__ x, const int* __restrict__ xflag, long row0,
    const void* __restrict__ g, const int* __restrict__ gflag,
    const void* __restrict__ b, const int* __restrict__ bflag,
    float* __restrict__ o)
{
    const int row = blockIdx.x;
    const int tid = threadIdx.x;
    const int xf = xflag ? *xflag : 1;
    const long base = (row0 + row) * 512 + tid * 2;
    const float vx = ldflex(x, xf, base);
    const float vy = ldflex(x, xf, base + 1);
    float s  = vx + vy;
    float s2 = vx * vx + vy * vy;
    #pragma unroll
    for (int off = 32; off > 0; off >>= 1) {
        s  += __shfl_down(s, off);
        s2 += __shfl_down(s2, off);
    }
    __shared__ float ss[4], ss2[4];
    if ((tid & 63) == 0) { ss[tid >> 6] = s; ss2[tid >> 6] = s2; }
    __syncthreads();
    const float ts   = ss[0] + ss[1] + ss[2] + ss[3];
    const float ts2  = ss2[0] + ss2[1] + ss2[2] + ss2[3];
    const float mean = ts * (1.0f / 512.0f);
    const float var  = ts2 * (1.0f / 512.0f) - mean * mean;
    const float rstd = rsqrtf(var + 1e-5f);
    const int gf = *gflag, bff = *bflag;
    float2 r;
    r.x = (vx - mean) * rstd * ldflex(g, gf, tid * 2)     + ldflex(b, bff, tid * 2);
    r.y = (vy - mean) * rstd * ldflex(g, gf, tid * 2 + 1) + ldflex(b, bff, tid * 2 + 1);
    ((float2*)(o + (long)row * 512))[tid] = r;
}

// ---------------------------------------------------------------------------
// Fused flash attention (fp32 compute/IO from scratch; table flexible dtype).
// One block per (b_local, head, 64-query tile). qkv: [bpc,N,3,H,64] fp32.
// o: [bpc,N,H,64] fp32. Rel-pos bias on the fly (H=W=32). LDS ~53 KB.
// ---------------------------------------------------------------------------
__global__ __launch_bounds__(256) void attn_fused(
    const float* __restrict__ qkv,
    const void* __restrict__ table, const int* __restrict__ tflag,
    float* __restrict__ o)
{
    __shared__ float Qt [64][LDP];  // Qt[d][r]
    __shared__ float KSt[64][LDP];  // Kt[d][c], later St[kk][r]
    __shared__ float Vs [64][LDP];  // Vs[kk][d]
    __shared__ float mrow[64], lrow[64], arow[64];
    __shared__ float pred[4][64];

    const int tid  = threadIdx.x;
    const int tx   = tid & 15, ty = tid >> 4;
    const int lane = tid & 63, wv = tid >> 6;
    const int q0 = blockIdx.x * 64;
    const int h  = blockIdx.y;
    const int b  = blockIdx.z;
    const int tf = *tflag;

    #pragma unroll
    for (int i = 0; i < 4; ++i) {
        const int f4i = tid + i * 256;
        const int r   = f4i >> 4;
        const int dd  = (f4i & 15) << 2;
        const f32x4 q = *(const f32x4*)&qkv[(long)((b * 1024 + q0 + r) * 3 + 0) * 512 + h * 64 + dd];
        Qt[dd + 0][r] = q[0]; Qt[dd + 1][r] = q[1];
        Qt[dd + 2][r] = q[2]; Qt[dd + 3][r] = q[3];
    }
    if (tid < 64) { mrow[tid] = -1e30f; lrow[tid] = 0.0f; }

    float oacc[4][4] = {};

    for (int kt = 0; kt < 16; ++kt) {
        const int k0 = kt * 64;
        __syncthreads();
        #pragma unroll
        for (int i = 0; i < 4; ++i) {
            const int f4i = tid + i * 256;
            const int r   = f4i >> 4;
            const int dd  = (f4i & 15) << 2;
            const f32x4 kv = *(const f32x4*)&qkv[(long)((b * 1024 + k0 + r) * 3 + 1) * 512 + h * 64 + dd];
            KSt[dd + 0][r] = kv[0]; KSt[dd + 1][r] = kv[1];
            KSt[dd + 2][r] = kv[2]; KSt[dd + 3][r] = kv[3];
            const f32x4 vv = *(const f32x4*)&qkv[(long)((b * 1024 + k0 + r) * 3 + 2) * 512 + h * 64 + dd];
            *(f32x4*)&Vs[r][dd] = vv;
        }
        __syncthreads();

        float s[4][4] = {};
        #pragma unroll
        for (int d = 0; d < 64; ++d) {
            const f32x4 av = *(const f32x4*)&Qt[d][ty << 2];
            const f32x4 bv = *(const f32x4*)&KSt[d][tx << 2];
            #pragma unroll
            for (int i = 0; i < 4; ++i)
                #pragma unroll
                for (int j = 0; j < 4; ++j)
                    s[i][j] = fmaf(av[i], bv[j], s[i][j]);
        }
        __syncthreads();   // Kt consumed; reuse as St

        #pragma unroll
        for (int i = 0; i < 4; ++i) {
            #pragma unroll
            for (int j = 0; j < 4; ++j) {
                const int qi = q0 + (ty << 2) + i;
                const int kj = k0 + (tx << 2) + j;
                const int dy = (qi >> 5) - (kj >> 5);
                const int dx = (qi & 31) - (kj & 31);
                int idx = (dy + 31) * 63 + (dx + 31);
                idx = idx > 224 ? 224 : idx;
                KSt[(tx << 2) + j][(ty << 2) + i] =
                    s[i][j] * 0.125f + ldflex(table, tf, idx * 8 + h);
            }
        }
        __syncthreads();

        float pm = -1e30f;
        #pragma unroll
        for (int k = 0; k < 16; ++k) pm = fmaxf(pm, KSt[wv * 16 + k][lane]);
        pred[wv][lane] = pm;
        __syncthreads();
        if (tid < 64) {
            const float mt   = fmaxf(fmaxf(pred[0][tid], pred[1][tid]),
                                     fmaxf(pred[2][tid], pred[3][tid]));
            const float mold = mrow[tid];
            const float mnew = fmaxf(mold, mt);
            mrow[tid] = mnew;
            arow[tid] = __expf(mold - mnew);
        }
        __syncthreads();
        const float mn = mrow[lane];
        float ps = 0.0f;
        #pragma unroll
        for (int k = 0; k < 16; ++k) {
            const float p = __expf(KSt[wv * 16 + k][lane] - mn);
            KSt[wv * 16 + k][lane] = p;
            ps += p;
        }
        pred[wv][lane] = ps;
        __syncthreads();
        if (tid < 64)
            lrow[tid] = lrow[tid] * arow[tid]
                      + pred[0][tid] + pred[1][tid] + pred[2][tid] + pred[3][tid];
        __syncthreads();

        #pragma unroll
        for (int i = 0; i < 4; ++i) {
            const float al = arow[(ty << 2) + i];
            #pragma unroll
            for (int j = 0; j < 4; ++j) oacc[i][j] *= al;
        }
        #pragma unroll
        for (int kk = 0; kk < 64; ++kk) {
            const f32x4 pv = *(const f32x4*)&KSt[kk][ty << 2];
            const f32x4 vv = *(const f32x4*)&Vs[kk][tx << 2];
            #pragma unroll
            for (int i = 0; i < 4; ++i)
                #pragma unroll
                for (int j = 0; j < 4; ++j)
                    oacc[i][j] = fmaf(pv[i], vv[j], oacc[i][j]);
        }
    }
    __syncthreads();

    #pragma unroll
    for (int i = 0; i < 4; ++i) {
        const int r = (ty << 2) + i;
        const float inv = 1.0f / lrow[r];
        f32x4 ov;
        #pragma unroll
        for (int j = 0; j < 4; ++j) ov[j] = oacc[i][j] * inv;
        *(f32x4*)&o[(long)((b * 1024 + q0 + r) * 8 + h) * 64 + (tx << 2)] = ov;
    }
}

extern "C" void kernel_launch(void* const* d_in, const int* in_sizes, int n_in,
                              void* d_out, int out_size, void* d_ws, size_t ws_size,
                              hipStream_t stream)
{
    (void)n_in; (void)out_size;
    float* out = (float*)d_out;   // output is fp32 (r2 evidence: 67 MB write OK)

    constexpr int B = 32, N = 1024;

    // ws layout: [0,256): 13 dtype flags (int).  [256,...): fp32 scratch.
    int* flags = (int*)d_ws;
    for (int t = 0; t < 13; ++t)
        sniff_dtype<<<1, 64, 0, stream>>>((const unsigned short*)d_in[t],
                                          in_sizes[t], flags + t);

    // fp32 scratch per batch: Ln 512 + Hd 2048 (qkv 1536 fits) + Ao 512
    //   = 1024*3072*4 B = 12.58 MB.
    float* S = (float*)((char*)d_ws + 256);
    const size_t bytes_per_batch = (size_t)N * 3072 * sizeof(float);
    int bpc = (int)((ws_size - 256) / bytes_per_batch);
    if (bpc < 1) bpc = 1;
    if (bpc > B) bpc = B;

    float* Ln = S;
    float* Hd = Ln + (size_t)bpc * N * 512;
    float* Ao = Hd + (size_t)bpc * N * 2048;

    // Phase 1: LN1 -> qkv -> attention -> proj (+bias, +x residual) -> out
    for (int b0 = 0; b0 < B; b0 += bpc) {
        const int nb   = (B - b0) < bpc ? (B - b0) : bpc;
        const int rows = nb * N;
        const long r0  = (long)b0 * N;

        layernorm_512<<<rows, 256, 0, stream>>>(
            d_in[0], flags + 0, r0, d_in[8], flags + 8, d_in[9], flags + 9, Ln);
        gemm_bt<<<dim3(24, rows / 64), 256, 0, stream>>>(
            Ln, d_in[1], flags + 1, Hd, 1536, 512,
            nullptr, nullptr, nullptr, nullptr, 0, 0);
        attn_fused<<<dim3(16, 8, nb), 256, 0, stream>>>(
            Hd, d_in[12], flags + 12, Ao);
        gemm_bt<<<dim3(8, rows / 64), 256, 0, stream>>>(
            Ao, d_in[2], flags + 2, out + r0 * 512, 512, 512,
            d_in[3], flags + 3, d_in[0], flags + 0, r0, 0);
    }

    // Phase 2: LN2 -> mlp1 (+bias, gelu) -> mlp2 (+bias, +residual in-place)
    for (int b0 = 0; b0 < B; b0 += bpc) {
        const int nb   = (B - b0) < bpc ? (B - b0) : bpc;
        const int rows = nb * N;
        const long r0  = (long)b0 * N;

        layernorm_512<<<rows, 256, 0, stream>>>(
            out + r0 * 512, nullptr, 0, d_in[10], flags + 10, d_in[11], flags + 11, Ln);
        gemm_bt<<<dim3(32, rows / 64), 256, 0, stream>>>(
            Ln, d_in[4], flags + 4, Hd, 2048, 512,
            d_in[5], flags + 5, nullptr, nullptr, 0, 1);
        gemm_bt<<<dim3(8, rows / 64), 256, 0, stream>>>(
            Hd, d_in[6], flags + 6, out + r0 * 512, 512, 2048,
            d_in[7], flags + 7, out + r0 * 512, nullptr, 0, 0);
    }
}

// Round 7
// 1603.693 us; speedup vs baseline: 6.8590x; 6.8590x over previous
//
#include <hip/hip_runtime.h>

typedef short bf16x8 __attribute__((ext_vector_type(8)));
typedef float f32x4 __attribute__((ext_vector_type(4)));
typedef unsigned short us8 __attribute__((ext_vector_type(8)));

__device__ __forceinline__ float bf2f(unsigned short u) {
    union { unsigned i; float f; } v; v.i = ((unsigned)u) << 16; return v.f;
}
__device__ __forceinline__ unsigned short f2bf(float f) {
    union { float f; unsigned i; } v; v.f = f;
    unsigned r = v.i + 0x7fffu + ((v.i >> 16) & 1u);   // RNE
    return (unsigned short)(r >> 16);
}
__device__ __forceinline__ float ldflex(const void* p, int isf32, long i) {
    return isf32 ? ((const float*)p)[i] : bf2f(((const unsigned short*)p)[i]);
}
__device__ __forceinline__ float gelu_exact(float v) {
    return 0.5f * v * (1.0f + erff(v * 0.70710678118654752f));
}
__device__ __forceinline__ bf16x8 pack8(const float* s) {
    bf16x8 r;
    #pragma unroll
    for (int i = 0; i < 8; ++i) r[i] = (short)f2bf(s[i]);
    return r;
}
__device__ __forceinline__ us8 pack8u(const float* s) {
    us8 r;
    #pragma unroll
    for (int i = 0; i < 8; ++i) r[i] = f2bf(s[i]);
    return r;
}

// ---------------------------------------------------------------------------
// Fused dtype sniffer: block i classifies tensor i. 1=fp32, 0=bf16.
// (same discriminator that passed in r6)
// ---------------------------------------------------------------------------
struct SniffArgs { const void* p[13]; int n[13]; };

__global__ __launch_bounds__(64) void sniff_all(SniffArgs a, int* __restrict__ flags)
{
    const unsigned short* buf = (const unsigned short*)a.p[blockIdx.x];
    const int n_elems = a.n[blockIdx.x];
    __shared__ int cnt[3];
    if (threadIdx.x < 3) cnt[threadIdx.x] = 0;
    __syncthreads();
    int K = n_elems / 2; if (K > 1024) K = 1024; if (K < 1) K = 1;
    int ins = 0, ne = 0, no = 0;
    for (int i = threadIdx.x; i < K; i += 64) {
        const unsigned lo = buf[2 * i], hi = buf[2 * i + 1];
        const unsigned e = (lo >> 7) & 0xFF;
        ins += (lo != 0 && (e < 90 || e > 160)) ? 1 : 0;
        ne  += (lo != 0);
        no  += (hi != 0);
    }
    atomicAdd(&cnt[0], ins); atomicAdd(&cnt[1], ne); atomicAdd(&cnt[2], no);
    __syncthreads();
    if (threadIdx.x == 0)
        flags[blockIdx.x] = (cnt[0] * 10 > K) || (cnt[1] * 10 < K && cnt[2] * 2 > K);
}

// ---------------------------------------------------------------------------
// MFMA GEMM: C(fp32) = A(fp32)[M,K] @ W[Nout,K]^T (+bias)(+gelu)(+resid).
// W/bias/resid flex dtype. 256 thr = 4 waves; 128x128 tile; BK=32; wave ->
// 64x64 via 4x4 MFMA 16x16x32_bf16 (fp32->bf16 convert at staging).
// Fragment maps (HW-verified): A/B frag [m|n=lane&15][k=quad*8+j];
// C/D: col=lane&15, row=quad*4+reg.
// ---------------------------------------------------------------------------
__global__ __launch_bounds__(256) void gemm_mfma(
    const float* __restrict__ A, const void* __restrict__ W,
    const int* __restrict__ wflag, float* C, int Nout, int K,
    const void* __restrict__ bias, const int* __restrict__ bflag,
    const void* resid, const int* rflag, long resid_row0, int act)
{
    __shared__ unsigned short As[128 * 32];   // [row][k], 64 B rows
    __shared__ unsigned short Bs[128 * 32];
    const int tid  = threadIdx.x;
    const int lane = tid & 63, wv = tid >> 6;
    const int wrow = wv >> 1, wcol = wv & 1;
    const int bm = blockIdx.y * 128, bn = blockIdx.x * 128;
    const int fm = lane & 15, quad = lane >> 4;
    const int wf = *wflag;

    f32x4 acc[4][4] = {};

    for (int k0 = 0; k0 < K; k0 += 32) {
        us8 va[2], vb[2];
        #pragma unroll
        for (int p = 0; p < 2; ++p) {
            const int e   = (p * 256 + tid) * 8;
            const int row = e >> 5;
            const int kk  = e & 31;
            float t[8];
            *(f32x4*)&t[0] = *(const f32x4*)&A[(long)(bm + row) * K + k0 + kk];
            *(f32x4*)&t[4] = *(const f32x4*)&A[(long)(bm + row) * K + k0 + kk + 4];
            va[p] = pack8u(t);
            if (wf) {
                const float* wp = &((const float*)W)[(long)(bn + row) * K + k0 + kk];
                *(f32x4*)&t[0] = *(const f32x4*)wp;
                *(f32x4*)&t[4] = *(const f32x4*)(wp + 4);
                vb[p] = pack8u(t);
            } else {
                vb[p] = *(const us8*)&((const unsigned short*)W)[(long)(bn + row) * K + k0 + kk];
            }
        }
        __syncthreads();   // prior iter's frag reads done
        #pragma unroll
        for (int p = 0; p < 2; ++p) {
            const int e = (p * 256 + tid) * 8;
            *(us8*)&As[e] = va[p];
            *(us8*)&Bs[e] = vb[p];
        }
        __syncthreads();   // tiles ready

        bf16x8 af[4], bf[4];
        #pragma unroll
        for (int t = 0; t < 4; ++t) {
            af[t] = *(const bf16x8*)&As[(wrow * 64 + t * 16 + fm) * 32 + quad * 8];
            bf[t] = *(const bf16x8*)&Bs[(wcol * 64 + t * 16 + fm) * 32 + quad * 8];
        }
        #pragma unroll
        for (int i = 0; i < 4; ++i)
            #pragma unroll
            for (int j = 0; j < 4; ++j)
                acc[i][j] = __builtin_amdgcn_mfma_f32_16x16x32_bf16(
                                af[i], bf[j], acc[i][j], 0, 0, 0);
    }

    const int bfl = bias  ? *bflag : 1;
    const int rfl = resid ? (rflag ? *rflag : 1) : 1;
    const int crow0 = bm + wrow * 64, ccol0 = bn + wcol * 64;
    #pragma unroll
    for (int j = 0; j < 4; ++j) {
        const int col = ccol0 + j * 16 + fm;
        const float bv = bias ? ldflex(bias, bfl, col) : 0.0f;
        #pragma unroll
        for (int i = 0; i < 4; ++i) {
            #pragma unroll
            for (int r = 0; r < 4; ++r) {
                const int row = crow0 + i * 16 + quad * 4 + r;
                float v = acc[i][j][r] + bv;
                if (act)   v = gelu_exact(v);
                if (resid) v += ldflex(resid, rfl, (resid_row0 + row) * (long)Nout + col);
                C[(long)row * Nout + col] = v;
            }
        }
    }
}

// ---------------------------------------------------------------------------
// LayerNorm over rows of 512. Flex-dtype x/g/b; fp32 out. (r6-proven)
// ---------------------------------------------------------------------------
__global__ __launch_bounds__(256) void layernorm_512(
    const void* __restrict__ x, const int* __restrict__ xflag, long row0,
    const void* __restrict__ g, const int* __restrict__ gflag,
    const void* __restrict__ b, const int* __restrict__ bflag,
    float* __restrict__ o)
{
    const int row = blockIdx.x;
    const int tid = threadIdx.x;
    const int xf = xflag ? *xflag : 1;
    const long base = (row0 + row) * 512 + tid * 2;
    const float vx = ldflex(x, xf, base);
    const float vy = ldflex(x, xf, base + 1);
    float s  = vx + vy;
    float s2 = vx * vx + vy * vy;
    #pragma unroll
    for (int off = 32; off > 0; off >>= 1) {
        s  += __shfl_down(s, off);
        s2 += __shfl_down(s2, off);
    }
    __shared__ float ss[4], ss2[4];
    if ((tid & 63) == 0) { ss[tid >> 6] = s; ss2[tid >> 6] = s2; }
    __syncthreads();
    const float ts   = ss[0] + ss[1] + ss[2] + ss[3];
    const float ts2  = ss2[0] + ss2[1] + ss2[2] + ss2[3];
    const float mean = ts * (1.0f / 512.0f);
    const float var  = ts2 * (1.0f / 512.0f) - mean * mean;
    const float rstd = rsqrtf(var + 1e-5f);
    const int gf = *gflag, bff = *bflag;
    float2 r;
    r.x = (vx - mean) * rstd * ldflex(g, gf, tid * 2)     + ldflex(b, bff, tid * 2);
    r.y = (vy - mean) * rstd * ldflex(g, gf, tid * 2 + 1) + ldflex(b, bff, tid * 2 + 1);
    ((float2*)(o + (long)row * 512))[tid] = r;
}

// ---------------------------------------------------------------------------
// MFMA flash attention. Block = (64 queries, head, batch); 4 waves; each wave
// owns 16 q-rows. qkv fp32 [b,n,3,H,64] (own scratch); o fp32 [b,n,H,64].
// Per 64-key tile: QK^T (MFMA) -> in-register online softmax (C-layout rows
// quad*4+r, 16-lane shfl_xor groups) -> P via LDS (C->A layout, m120) ->
// PV (MFMA, V transposed in LDS). Rel-pos bias from LDS-cached table.
// LDS ~35 KB.
// ---------------------------------------------------------------------------
__global__ __launch_bounds__(256, 3) void attn_mfma(
    const float* __restrict__ qkv,
    const void* __restrict__ table, const int* __restrict__ tflag,
    float* __restrict__ o)
{
    __shared__ unsigned short Ks[64 * 72];     // [key][d]   9.2 KB
    __shared__ unsigned short Vt[64 * 72];     // [d][key]   9.2 KB
    __shared__ unsigned short Pl[4][16 * 72];  // per-wave P [q][key] 9.2 KB
    __shared__ float Tb[1800];                 // bias table 7.2 KB

    const int tid  = threadIdx.x;
    const int lane = tid & 63, wv = tid >> 6;
    const int fm = lane & 15, quad = lane >> 4;
    const int q0 = blockIdx.x * 64;
    const int h  = blockIdx.y;
    const int b  = blockIdx.z;

    {   // cache bias table (flex dtype)
        const int tf = *tflag;
        for (int i = tid; i < 1800; i += 256) Tb[i] = ldflex(table, tf, i);
    }

    // Q fragments: A[m=fm -> q][k=quad*8+j -> d], 2 chains (d 0..31, 32..63)
    bf16x8 qa[2];
    {
        const float* qb = &qkv[(long)((b * 1024 + q0 + wv * 16 + fm) * 3 + 0) * 512
                               + h * 64 + quad * 8];
        float t[8];
        #pragma unroll
        for (int c = 0; c < 2; ++c) {
            *(f32x4*)&t[0] = *(const f32x4*)(qb + c * 32);
            *(f32x4*)&t[4] = *(const f32x4*)(qb + c * 32 + 4);
            qa[c] = pack8(t);
        }
    }

    f32x4 acc[4] = {};          // O accumulator: col-tile c -> d, rows quad*4+r
    float mrow[4] = {-1e30f, -1e30f, -1e30f, -1e30f};
    float lrow[4] = {};

    const int key_s = tid >> 2;           // staging: key row
    const int dc    = (tid & 3) * 16;     // staging: d chunk

    for (int kt = 0; kt < 16; ++kt) {
        const int k0 = kt * 64;
        __syncthreads();   // protect Ks/Vt (and Tb on first iter)
        {
            float t[16];
            const float* kp = &qkv[(long)((b * 1024 + k0 + key_s) * 3 + 1) * 512 + h * 64 + dc];
            #pragma unroll
            for (int i = 0; i < 4; ++i) *(f32x4*)&t[4 * i] = *(const f32x4*)(kp + 4 * i);
            *(us8*)&Ks[key_s * 72 + dc]     = pack8u(t);
            *(us8*)&Ks[key_s * 72 + dc + 8] = pack8u(t + 8);
            const float* vp = &qkv[(long)((b * 1024 + k0 + key_s) * 3 + 2) * 512 + h * 64 + dc];
            #pragma unroll
            for (int i = 0; i < 4; ++i) *(f32x4*)&t[4 * i] = *(const f32x4*)(vp + 4 * i);
            #pragma unroll
            for (int i = 0; i < 16; ++i) Vt[(dc + i) * 72 + key_s] = f2bf(t[i]);
        }
        __syncthreads();

        // S = Q K^T  (4 col-tiles x 2 k-chains)
        f32x4 sv[4];
        #pragma unroll
        for (int c = 0; c < 4; ++c) {
            f32x4 z = {};
            z = __builtin_amdgcn_mfma_f32_16x16x32_bf16(
                    qa[0], *(const bf16x8*)&Ks[(c * 16 + fm) * 72 + quad * 8], z, 0, 0, 0);
            z = __builtin_amdgcn_mfma_f32_16x16x32_bf16(
                    qa[1], *(const bf16x8*)&Ks[(c * 16 + fm) * 72 + 32 + quad * 8], z, 0, 0, 0);
            sv[c] = z;
        }

        // scale + rel-pos bias (C layout: row q=quad*4+r, col key=c*16+fm)
        #pragma unroll
        for (int c = 0; c < 4; ++c) {
            const int kj = k0 + c * 16 + fm;
            const int ky = kj >> 5, kx = kj & 31;
            #pragma unroll
            for (int r = 0; r < 4; ++r) {
                const int qi = q0 + wv * 16 + quad * 4 + r;
                const int dy = (qi >> 5) - ky;
                const int dx = (qi & 31) - kx;
                int idx = (dy + 31) * 63 + (dx + 31);
                idx = idx > 224 ? 224 : idx;
                sv[c][r] = sv[c][r] * 0.125f + Tb[idx * 8 + h];
            }
        }

        // online softmax per q-row (16-lane groups: lanes share quad)
        float alpha[4];
        #pragma unroll
        for (int r = 0; r < 4; ++r) {
            float mr = fmaxf(fmaxf(sv[0][r], sv[1][r]), fmaxf(sv[2][r], sv[3][r]));
            #pragma unroll
            for (int off = 1; off < 16; off <<= 1) mr = fmaxf(mr, __shfl_xor(mr, off));
            const float mnew = fmaxf(mrow[r], mr);
            alpha[r] = __expf(mrow[r] - mnew);
            mrow[r] = mnew;
            float ps = 0.0f;
            #pragma unroll
            for (int c = 0; c < 4; ++c) {
                const float p = __expf(sv[c][r] - mnew);
                sv[c][r] = p;
                ps += p;
            }
            #pragma unroll
            for (int off = 1; off < 16; off <<= 1) ps += __shfl_xor(ps, off);
            lrow[r] = lrow[r] * alpha[r] + ps;
        }

        // P: C layout -> LDS [q][key] (per-wave private region)
        unsigned short* Pw = Pl[wv];
        #pragma unroll
        for (int c = 0; c < 4; ++c)
            #pragma unroll
            for (int r = 0; r < 4; ++r)
                Pw[(quad * 4 + r) * 72 + c * 16 + fm] = f2bf(sv[c][r]);

        // PV: A frag = P[q=fm][key=chain*32+quad*8+j]; B frag = Vt[d][key]
        const bf16x8 ap0 = *(const bf16x8*)&Pw[fm * 72 + quad * 8];
        const bf16x8 ap1 = *(const bf16x8*)&Pw[fm * 72 + 32 + quad * 8];
        #pragma unroll
        for (int c = 0; c < 4; ++c) {
            #pragma unroll
            for (int r = 0; r < 4; ++r) acc[c][r] *= alpha[r];
            acc[c] = __builtin_amdgcn_mfma_f32_16x16x32_bf16(
                        ap0, *(const bf16x8*)&Vt[(c * 16 + fm) * 72 + quad * 8], acc[c], 0, 0, 0);
            acc[c] = __builtin_amdgcn_mfma_f32_16x16x32_bf16(
                        ap1, *(const bf16x8*)&Vt[(c * 16 + fm) * 72 + 32 + quad * 8], acc[c], 0, 0, 0);
        }
    }

    float rinv[4];
    #pragma unroll
    for (int r = 0; r < 4; ++r) rinv[r] = 1.0f / lrow[r];
    #pragma unroll
    for (int c = 0; c < 4; ++c)
        #pragma unroll
        for (int r = 0; r < 4; ++r)
            o[(long)(b * 1024 + q0 + wv * 16 + quad * 4 + r) * 512 + h * 64 + c * 16 + fm]
                = acc[c][r] * rinv[r];
}

extern "C" void kernel_launch(void* const* d_in, const int* in_sizes, int n_in,
                              void* d_out, int out_size, void* d_ws, size_t ws_size,
                              hipStream_t stream)
{
    (void)n_in; (void)out_size;
    float* out = (float*)d_out;

    constexpr int B = 32, N = 1024;

    int* flags = (int*)d_ws;
    {
        SniffArgs sa;
        for (int t = 0; t < 13; ++t) { sa.p[t] = d_in[t]; sa.n[t] = in_sizes[t]; }
        sniff_all<<<13, 64, 0, stream>>>(sa, flags);
    }

    float* S = (float*)((char*)d_ws + 256);
    const size_t bytes_per_batch = (size_t)N * 3072 * sizeof(float);
    int bpc = (int)((ws_size - 256) / bytes_per_batch);
    if (bpc < 1) bpc = 1;
    if (bpc > B) bpc = B;

    float* Ln = S;
    float* Hd = Ln + (size_t)bpc * N * 512;
    float* Ao = Hd + (size_t)bpc * N * 2048;

    // Phase 1: LN1 -> qkv -> attention -> proj (+bias, +x residual)
    for (int b0 = 0; b0 < B; b0 += bpc) {
        const int nb   = (B - b0) < bpc ? (B - b0) : bpc;
        const int rows = nb * N;
        const long r0  = (long)b0 * N;

        layernorm_512<<<rows, 256, 0, stream>>>(
            d_in[0], flags + 0, r0, d_in[8], flags + 8, d_in[9], flags + 9, Ln);
        gemm_mfma<<<dim3(12, rows / 128), 256, 0, stream>>>(
            Ln, d_in[1], flags + 1, Hd, 1536, 512,
            nullptr, nullptr, nullptr, nullptr, 0, 0);
        attn_mfma<<<dim3(16, 8, nb), 256, 0, stream>>>(
            Hd, d_in[12], flags + 12, Ao);
        gemm_mfma<<<dim3(4, rows / 128), 256, 0, stream>>>(
            Ao, d_in[2], flags + 2, out + r0 * 512, 512, 512,
            d_in[3], flags + 3, d_in[0], flags + 0, r0, 0);
    }

    // Phase 2: LN2 -> mlp1 (+bias, gelu) -> mlp2 (+bias, +residual in-place)
    for (int b0 = 0; b0 < B; b0 += bpc) {
        const int nb   = (B - b0) < bpc ? (B - b0) : bpc;
        const int rows = nb * N;
        const long r0  = (long)b0 * N;

        layernorm_512<<<rows, 256, 0, stream>>>(
            out + r0 * 512, nullptr, 0, d_in[10], flags + 10, d_in[11], flags + 11, Ln);
        gemm_mfma<<<dim3(16, rows / 128), 256, 0, stream>>>(
            Ln, d_in[4], flags + 4, Hd, 2048, 512,
            d_in[5], flags + 5, nullptr, nullptr, 0, 1);
        gemm_mfma<<<dim3(4, rows / 128), 256, 0, stream>>>(
            Hd, d_in[6], flags + 6, out + r0 * 512, 512, 2048,
            d_in[7], flags + 7, out + r0 * 512, nullptr, 0, 0);
    }
}